// Round 4
// baseline (735.012 us; speedup 1.0000x reference)
//
#include <hip/hip_runtime.h>
#include <math.h>

#define B_ 64
#define T_ 2048
#define DL 1024
#define DE 512
#define DA 128
#define NF 32
#define KW 31
#define PADW 15
#define TT 128

typedef short bf16x8 __attribute__((ext_vector_type(8)));
typedef float f32x4 __attribute__((ext_vector_type(4)));

union BF8 { bf16x8 v; unsigned u[4]; };

// truncation split of 2 floats -> packed hi pair + lo pair
__device__ __forceinline__ void split2_trunc(float x0, float x1, unsigned &h01, unsigned &l01) {
    unsigned u0 = __float_as_uint(x0), u1 = __float_as_uint(x1);
    h01 = __builtin_amdgcn_perm(u1, u0, 0x07060302u);
    float l0 = x0 - __uint_as_float(u0 & 0xFFFF0000u);
    float l1 = x1 - __uint_as_float(u1 & 0xFFFF0000u);
    l01 = __builtin_amdgcn_perm(__float_as_uint(l1), __float_as_uint(l0), 0x07060302u);
}

__device__ __forceinline__ void split1_trunc(float x, unsigned short &h, unsigned short &l) {
    unsigned u = __float_as_uint(x);
    h = (unsigned short)(u >> 16);
    float lf = x - __uint_as_float(u & 0xFFFF0000u);
    l = (unsigned short)(__float_as_uint(lf) >> 16);
}

__device__ __forceinline__ float fast_tanh(float x) {
    x = fminf(fmaxf(x, -15.f), 15.f);
    float e2 = __expf(2.f * x);
    return (e2 - 1.f) * __builtin_amdgcn_rcpf(e2 + 1.f);
}

// bf16 fragment-linear offset (B operand), 128 rows x 32 k per chunk:
// hi at off, lo at off+4096
__device__ __forceinline__ int frag_off(int row, int kin) {
    return (((row >> 4) * 64 + (kin >> 3) * 16 + (row & 15)) << 3) + (kin & 7);
}

// fp32 fragment-linear float-index (A operand), 128 rows x 32 k per chunk:
// unit16B = (r>>4)*128 + ((k>>2)&1)*64 + (k>>3)*16 + (r&15); float = unit*4 + (k&3)
__device__ __forceinline__ int a_fidx(int r, int k) {
    int unit = ((r >> 4) << 7) + (((k >> 2) & 1) << 6) + ((k >> 3) << 4) + (r & 15);
    return (unit << 2) + (k & 3);
}

// ---- prep: Wm [128][512] fp32 -> swizzled hi/lo bf16 fragment-linear (RNE) ----
__global__ __launch_bounds__(256) void prep_kernel(const float* __restrict__ Wm,
                                                   unsigned short* __restrict__ Bsw) {
    int i = blockIdx.x * 256 + threadIdx.x;  // 65536
    int a = i >> 9, k = i & 511;
    float x = Wm[i];
    unsigned u = __float_as_uint(x);
    unsigned short h = (unsigned short)((u + 0x7FFFu + ((u >> 16) & 1u)) >> 16);
    float lf = x - __uint_as_float((unsigned)h << 16);
    unsigned ul = __float_as_uint(lf);
    unsigned short l = (unsigned short)((ul + 0x7FFFu + ((ul >> 16) & 1u)) >> 16);
    int c = k >> 5, kin = k & 31;
    size_t base = (size_t)c * 8192 + frag_off(a, kin);
    Bsw[base] = h;
    Bsw[base + 4096] = l;
}

// ---- q = query @ Wq.T + bq ----
__global__ __launch_bounds__(128) void q_kernel(const float* __restrict__ query,
                                                const float* __restrict__ Wq,
                                                const float* __restrict__ bq,
                                                float* __restrict__ qbuf) {
    int b = blockIdx.x;
    int a = threadIdx.x;
    __shared__ __align__(16) float qs[DL];
    for (int i = threadIdx.x; i < DL; i += 128) qs[i] = query[(size_t)b * DL + i];
    __syncthreads();
    const float* wrow = Wq + (size_t)a * DL;
    float acc = 0.f;
#pragma unroll 8
    for (int i = 0; i < DL; i += 4) {
        float4 w = *(const float4*)(wrow + i);
        float4 q4 = *(const float4*)(qs + i);
        acc += w.x * q4.x + w.y * q4.y + w.z * q4.z + w.w * q4.w;
    }
    qbuf[(size_t)b * DA + a] = acc + bq[a];
}

// ---- energies: A via global_load_lds (fp32, fragment-linear swizzled source),
//      register split to bf16 hi/lo at consume, one barrier per chunk ----
__global__ __launch_bounds__(256, 2) void energy_kernel(
    const float* __restrict__ mem,            // [B,T,512]
    const float* __restrict__ attw,           // [B,2,T]
    const unsigned short* __restrict__ Bsw,   // swizzled Wm hi/lo
    const float* __restrict__ bm,
    const float* __restrict__ Wconv,          // [32,2,31]
    const float* __restrict__ Wloc,           // [128,32]
    const float* __restrict__ Wv,
    const float* __restrict__ bv,
    const float* __restrict__ qbuf,           // [B,128]
    float* __restrict__ e_out)                // [B,T]
{
    __shared__ __align__(16) float Abuf[2][4096];           // fp32 frag-linear, 16 KB each
    __shared__ __align__(16) unsigned short Bbuf[2][8192];  // bf16 hi|lo frag-linear, 16 KB each
    __shared__ float qb_s[DA], wv_s[DA];
    __shared__ float e_part[2][TT];

    const int tid = threadIdx.x;
    const int b = blockIdx.y;
    const int t0 = blockIdx.x * TT;
    const int lane = tid & 63;
    const int wave = tid >> 6;
    const int wm = wave & 1, wn = wave >> 1;
    const int m15 = lane & 15;
    const int kg = lane >> 4;

    // phase 1: scratch (aliases Abuf[1]): attw slice + wconv; Wloc frags -> Bbuf[1]
    float* attw_s  = Abuf[1];          // [2][160] = 320 floats
    float* wconv_s = Abuf[1] + 320;    // [32][64] = 2048 floats

    if (tid < DA) {
        qb_s[tid] = qbuf[(size_t)b * DA + tid] + bm[tid];
        wv_s[tid] = Wv[tid];
    }
    for (int i = tid; i < 2 * (TT + KW - 1); i += 256) {
        int c = i / 158, j = i % 158;
        int t = t0 - PADW + j;
        attw_s[c * 160 + j] = (t >= 0 && t < T_) ? attw[((size_t)b * 2 + c) * T_ + t] : 0.f;
    }
    for (int i = tid; i < NF * 2 * KW; i += 256) {
        int f = i / 62, r = i % 62;
        wconv_s[f * 64 + r] = Wconv[i];
    }
    for (int i = tid; i < DA * NF; i += 256) {
        int a = i >> 5, f = i & 31;
        unsigned short h, l;
        split1_trunc(Wloc[a * NF + f], h, l);
        int off = frag_off(a, f);
        Bbuf[1][off] = h;
        Bbuf[1][off + 4096] = l;
    }
    __syncthreads();

    // phase 2: conv -> Abuf[0] (fp32 fragment-linear)
    for (int i = tid; i < TT * NF; i += 256) {
        int t = i >> 5, f = i & 31;
        const float* w0 = wconv_s + f * 64;
        const float* a0 = attw_s + t;
        const float* a1 = attw_s + 160 + t;
        float s = 0.f;
#pragma unroll
        for (int k = 0; k < KW; ++k) s += w0[k] * a0[k] + w0[31 + k] * a1[k];
        Abuf[0][a_fidx(t, f)] = s;
    }
    __syncthreads();

    f32x4 acc[4][4];
#pragma unroll
    for (int mi = 0; mi < 4; ++mi)
#pragma unroll
        for (int ni = 0; ni < 4; ++ni) {
            f32x4 z = {0.f, 0.f, 0.f, 0.f};
            acc[mi][ni] = z;
        }

    // A-DMA per-lane source pointers (fragment-linear inverse map):
    // instr id = wave*4+it: rows ((id>>1)*16 + m15), float col = kg*8 + (id&1)*4
    const size_t mem_base = ((size_t)b * T_ + t0) * DE;
    const float* aptr[4];
#pragma unroll
    for (int it = 0; it < 4; ++it) {
        int id = wave * 4 + it;
        int r = (id >> 1) * 16 + m15;
        int col = kg * 8 + (id & 1) * 4;
        aptr[it] = mem + mem_base + (size_t)r * DE + col;
    }
    const unsigned short* bptr = Bsw + wave * 2048 + lane * 8;

    auto issue_A = [&](float* dst) {
#pragma unroll
        for (int it = 0; it < 4; ++it) {
            __builtin_amdgcn_global_load_lds(
                (const __attribute__((address_space(1))) unsigned*)aptr[it],
                (__attribute__((address_space(3))) unsigned*)((char*)dst + (wave * 4 + it) * 1024),
                16, 0, 0);
            aptr[it] += 32;  // next 32-k chunk
        }
    };
    auto issue_B = [&](unsigned short* dst) {
#pragma unroll
        for (int it = 0; it < 4; ++it) {
            __builtin_amdgcn_global_load_lds(
                (const __attribute__((address_space(1))) unsigned*)bptr,
                (__attribute__((address_space(3))) unsigned*)((char*)dst + wave * 4096 + it * 1024),
                16, 0, 0);
            bptr += 512;  // 1024 B
        }
        bptr += 6144;  // advance to next chunk (8192 ush total)
    };

    auto mfma_step = [&](const float* Ab, const unsigned short* Bb) {
        BF8 ah[4], al[4];
#pragma unroll
        for (int mi = 0; mi < 4; ++mi) {
            const float* p = Ab + (wm * 4 + mi) * 512 + lane * 4;
            f32x4 a0 = *(const f32x4*)p;           // k 0..3 of lane's 8
            f32x4 a1 = *(const f32x4*)(p + 256);   // k 4..7
            split2_trunc(a0.x, a0.y, ah[mi].u[0], al[mi].u[0]);
            split2_trunc(a0.z, a0.w, ah[mi].u[1], al[mi].u[1]);
            split2_trunc(a1.x, a1.y, ah[mi].u[2], al[mi].u[2]);
            split2_trunc(a1.z, a1.w, ah[mi].u[3], al[mi].u[3]);
        }
#pragma unroll
        for (int ni = 0; ni < 4; ++ni) {
            const unsigned short* q = Bb + ((wn * 4 + ni) * 64 + lane) * 8;
            bf16x8 bh = *(const bf16x8*)q;
            bf16x8 bl = *(const bf16x8*)(q + 4096);
#pragma unroll
            for (int mi = 0; mi < 4; ++mi) {
                acc[mi][ni] = __builtin_amdgcn_mfma_f32_16x16x32_bf16(ah[mi].v, bh, acc[mi][ni], 0, 0, 0);
                acc[mi][ni] = __builtin_amdgcn_mfma_f32_16x16x32_bf16(ah[mi].v, bl, acc[mi][ni], 0, 0, 0);
                acc[mi][ni] = __builtin_amdgcn_mfma_f32_16x16x32_bf16(al[mi].v, bh, acc[mi][ni], 0, 0, 0);
            }
        }
    };

    // prefetch chunk 0 while conv-chunk MFMA runs
    issue_A(Abuf[1]);
    issue_B(Bbuf[0]);
    mfma_step(Abuf[0], Bbuf[1]);   // conv/location chunk
    __syncthreads();               // drains DMA(0); conv reads done

    for (int c = 0; c < 16; ++c) {
        if (c < 15) {
            issue_A(Abuf[c & 1]);            // chunk c+1
            issue_B(Bbuf[(c + 1) & 1]);
        }
        mfma_step(Abuf[(c + 1) & 1], Bbuf[c & 1]);
        __syncthreads();
    }

    // epilogue: e[t] = bv + sum_a wv[a]*tanh(acc + qb[a])
    float wvr[4], qbr[4];
#pragma unroll
    for (int ni = 0; ni < 4; ++ni) {
        int a = wn * 64 + ni * 16 + m15;
        wvr[ni] = wv_s[a];
        qbr[ni] = qb_s[a];
    }
    float bvv = bv[0];
#pragma unroll
    for (int mi = 0; mi < 4; ++mi) {
#pragma unroll
        for (int reg = 0; reg < 4; ++reg) {
            float s = 0.f;
#pragma unroll
            for (int ni = 0; ni < 4; ++ni)
                s += wvr[ni] * fast_tanh(acc[mi][ni][reg] + qbr[ni]);
            s += __shfl_xor(s, 1, 64);
            s += __shfl_xor(s, 2, 64);
            s += __shfl_xor(s, 4, 64);
            s += __shfl_xor(s, 8, 64);
            if (m15 == 0)
                e_part[wn][wm * 64 + mi * 16 + kg * 4 + reg] = s;
        }
    }
    __syncthreads();
    if (tid < TT)
        e_out[(size_t)b * T_ + t0 + tid] = e_part[0][tid] + e_part[1][tid] + bvv;
}

// ---- softmax over T per b ----
__global__ __launch_bounds__(256) void softmax_kernel(const float* __restrict__ e,
                                                      float* __restrict__ wout) {
    int b = blockIdx.x;
    int tid = threadIdx.x;
    __shared__ float red[4];
    float v[8];
    float m = -1e30f;
#pragma unroll
    for (int r = 0; r < 8; ++r) {
        v[r] = e[(size_t)b * T_ + r * 256 + tid];
        m = fmaxf(m, v[r]);
    }
#pragma unroll
    for (int off = 1; off < 64; off <<= 1) m = fmaxf(m, __shfl_xor(m, off, 64));
    if ((tid & 63) == 0) red[tid >> 6] = m;
    __syncthreads();
    m = fmaxf(fmaxf(red[0], red[1]), fmaxf(red[2], red[3]));
    __syncthreads();
    float s = 0.f;
#pragma unroll
    for (int r = 0; r < 8; ++r) {
        v[r] = expf(v[r] - m);
        s += v[r];
    }
#pragma unroll
    for (int off = 1; off < 64; off <<= 1) s += __shfl_xor(s, off, 64);
    if ((tid & 63) == 0) red[tid >> 6] = s;
    __syncthreads();
    s = red[0] + red[1] + red[2] + red[3];
    float inv = 1.0f / s;
#pragma unroll
    for (int r = 0; r < 8; ++r) wout[(size_t)b * T_ + r * 256 + tid] = v[r] * inv;
}

// ---- context partials: 32 chunks of 64 t-rows (2048 blocks for TLP) ----
__global__ __launch_bounds__(256) void ctx_partial_kernel(const float* __restrict__ mem,
                                                          const float* __restrict__ w,
                                                          float* __restrict__ partial) {
    int b = blockIdx.y, tc = blockIdx.x;  // 32 chunks of 64 t
    int tid = threadIdx.x;
    __shared__ float ws_s[64];
    __shared__ float red[512];
    if (tid < 64) ws_s[tid] = w[(size_t)b * T_ + tc * 64 + tid];
    __syncthreads();
    int d = (tid & 127) * 4;
    int th = tid >> 7;  // two t-halves of 32
    const float* mp = mem + ((size_t)b * T_ + tc * 64 + th * 32) * DE + d;
    float a0 = 0.f, a1 = 0.f, a2 = 0.f, a3 = 0.f;
#pragma unroll 8
    for (int t = 0; t < 32; ++t) {
        float4 v = *(const float4*)(mp + (size_t)t * DE);
        float wv = ws_s[th * 32 + t];
        a0 += wv * v.x; a1 += wv * v.y; a2 += wv * v.z; a3 += wv * v.w;
    }
    if (th == 1) {
        float* r = red + (tid & 127) * 4;
        r[0] = a0; r[1] = a1; r[2] = a2; r[3] = a3;
    }
    __syncthreads();
    if (th == 0) {
        const float* r = red + tid * 4;
        float* pp = partial + ((size_t)b * 32 + tc) * DE + d;
        pp[0] = a0 + r[0]; pp[1] = a1 + r[1]; pp[2] = a2 + r[2]; pp[3] = a3 + r[3];
    }
}

// ---- reduce partials -> context ----
__global__ __launch_bounds__(512) void ctx_reduce_kernel(const float* __restrict__ partial,
                                                         float* __restrict__ ctx) {
    int b = blockIdx.x;
    int d = threadIdx.x;
    float s = 0.f;
#pragma unroll
    for (int j = 0; j < 32; ++j) s += partial[((size_t)b * 32 + j) * DE + d];
    ctx[(size_t)b * DE + d] = s;
}

extern "C" void kernel_launch(void* const* d_in, const int* in_sizes, int n_in,
                              void* d_out, int out_size, void* d_ws, size_t ws_size,
                              hipStream_t stream) {
    const float* query  = (const float*)d_in[0];
    const float* memory = (const float*)d_in[1];
    const float* attw   = (const float*)d_in[2];
    const float* Wq     = (const float*)d_in[3];
    const float* bq     = (const float*)d_in[4];
    const float* Wm     = (const float*)d_in[5];
    const float* bm     = (const float*)d_in[6];
    const float* Wconv  = (const float*)d_in[7];
    const float* Wloc   = (const float*)d_in[8];
    const float* Wv     = (const float*)d_in[9];
    const float* bv     = (const float*)d_in[10];

    float* out = (float*)d_out;
    float* ctx_out = out;          // [64,512]
    float* w_out = out + B_ * DE;  // [64,2048]

    float* ws = (float*)d_ws;
    float* qbuf = ws;                                  // 8192 f
    float* ebuf = qbuf + B_ * DA;                      // 131072 f
    float* partial = ebuf + (size_t)B_ * T_;           // 64*32*512 = 1048576 f
    unsigned short* Bsw = (unsigned short*)(partial + (size_t)B_ * 32 * DE);  // 131072 ush

    prep_kernel<<<dim3(DA * DE / 256), dim3(256), 0, stream>>>(Wm, Bsw);
    q_kernel<<<dim3(B_), dim3(128), 0, stream>>>(query, Wq, bq, qbuf);
    energy_kernel<<<dim3(T_ / TT, B_), dim3(256), 0, stream>>>(
        memory, attw, Bsw, bm, Wconv, Wloc, Wv, bv, qbuf, ebuf);
    softmax_kernel<<<dim3(B_), dim3(256), 0, stream>>>(ebuf, w_out);
    ctx_partial_kernel<<<dim3(32, B_), dim3(256), 0, stream>>>(memory, w_out, partial);
    ctx_reduce_kernel<<<dim3(B_), dim3(512), 0, stream>>>(partial, ctx_out);
}

// Round 5
// 730.360 us; speedup vs baseline: 1.0064x; 1.0064x over previous
//
#include <hip/hip_runtime.h>
#include <math.h>

#define B_ 64
#define T_ 2048
#define DL 1024
#define DE 512
#define DA 128
#define NF 32
#define KW 31
#define PADW 15
#define TT 128

typedef short bf16x8 __attribute__((ext_vector_type(8)));
typedef float f32x4 __attribute__((ext_vector_type(4)));

union BF8 { bf16x8 v; unsigned u[4]; };

// truncation split of 2 floats -> packed hi pair + lo pair (bf16)
__device__ __forceinline__ void split2_trunc(float x0, float x1, unsigned &h01, unsigned &l01) {
    unsigned u0 = __float_as_uint(x0), u1 = __float_as_uint(x1);
    h01 = __builtin_amdgcn_perm(u1, u0, 0x07060302u);
    float l0 = x0 - __uint_as_float(u0 & 0xFFFF0000u);
    float l1 = x1 - __uint_as_float(u1 & 0xFFFF0000u);
    l01 = __builtin_amdgcn_perm(__float_as_uint(l1), __float_as_uint(l0), 0x07060302u);
}

__device__ __forceinline__ void split1_trunc(float x, unsigned short &h, unsigned short &l) {
    unsigned u = __float_as_uint(x);
    h = (unsigned short)(u >> 16);
    float lf = x - __uint_as_float(u & 0xFFFF0000u);
    l = (unsigned short)(__float_as_uint(lf) >> 16);
}

__device__ __forceinline__ float fast_tanh(float x) {
    x = fminf(fmaxf(x, -15.f), 15.f);
    float e2 = __expf(2.f * x);
    return (e2 - 1.f) * __builtin_amdgcn_rcpf(e2 + 1.f);
}

// bf16 fragment-linear offset (B operand), 128 rows x 32 k per chunk: hi at off, lo at off+4096
__device__ __forceinline__ int frag_off(int row, int kin) {
    return (((row >> 4) * 64 + (kin >> 3) * 16 + (row & 15)) << 3) + (kin & 7);
}

// ---- prep: Wm [128][512] fp32 -> swizzled hi/lo bf16 fragment-linear (RNE) ----
__global__ __launch_bounds__(256) void prep_kernel(const float* __restrict__ Wm,
                                                   unsigned short* __restrict__ Bsw) {
    int i = blockIdx.x * 256 + threadIdx.x;  // 65536
    int a = i >> 9, k = i & 511;
    float x = Wm[i];
    unsigned u = __float_as_uint(x);
    unsigned short h = (unsigned short)((u + 0x7FFFu + ((u >> 16) & 1u)) >> 16);
    float lf = x - __uint_as_float((unsigned)h << 16);
    unsigned ul = __float_as_uint(lf);
    unsigned short l = (unsigned short)((ul + 0x7FFFu + ((ul >> 16) & 1u)) >> 16);
    int c = k >> 5, kin = k & 31;
    size_t base = (size_t)c * 8192 + frag_off(a, kin);
    Bsw[base] = h;
    Bsw[base + 4096] = l;
}

// ---- q = query @ Wq.T + bq ----
__global__ __launch_bounds__(128) void q_kernel(const float* __restrict__ query,
                                                const float* __restrict__ Wq,
                                                const float* __restrict__ bq,
                                                float* __restrict__ qbuf) {
    int b = blockIdx.x;
    int a = threadIdx.x;
    __shared__ __align__(16) float qs[DL];
    for (int i = threadIdx.x; i < DL; i += 128) qs[i] = query[(size_t)b * DL + i];
    __syncthreads();
    const float* wrow = Wq + (size_t)a * DL;
    float acc = 0.f;
#pragma unroll 8
    for (int i = 0; i < DL; i += 4) {
        float4 w = *(const float4*)(wrow + i);
        float4 q4 = *(const float4*)(qs + i);
        acc += w.x * q4.x + w.y * q4.y + w.z * q4.z + w.w * q4.w;
    }
    qbuf[(size_t)b * DA + a] = acc + bq[a];
}

// ---- energies: A+B staged by global_load_lds (coalesced source, XOR-swizzled A
//      layout), register split to bf16 at consume, one barrier per chunk ----
__global__ __launch_bounds__(256, 2) void energy_kernel(
    const float* __restrict__ mem,            // [B,T,512]
    const float* __restrict__ attw,           // [B,2,T]
    const unsigned short* __restrict__ Bsw,   // swizzled Wm hi/lo
    const float* __restrict__ bm,
    const float* __restrict__ Wconv,          // [32,2,31]
    const float* __restrict__ Wloc,           // [128,32]
    const float* __restrict__ Wv,
    const float* __restrict__ bv,
    const float* __restrict__ qbuf,           // [B,128]
    float* __restrict__ e_out)                // [B,T]
{
    // A: fp32, unit16B u = r*8 + (c ^ (r&7)), c = k>>2. 16 KB per buffer.
    __shared__ __align__(16) float Abuf[2][4096];
    // B: bf16 frag-linear [hi 4096 | lo 4096] ushorts. 16 KB per buffer.
    __shared__ __align__(16) unsigned short Bbuf[2][8192];
    __shared__ float qb_s[DA], wv_s[DA];
    __shared__ float e_part[2][TT];

    const int tid = threadIdx.x;
    const int b = blockIdx.y;
    const int t0 = blockIdx.x * TT;
    const int lane = tid & 63;
    const int wave = tid >> 6;
    const int wm = wave & 1, wn = wave >> 1;
    const int m15 = lane & 15;
    const int kg = lane >> 4;

    // phase 1 scratch aliases Abuf[0]
    float* attw_s  = Abuf[0];          // [2][160]
    float* wconv_s = Abuf[0] + 320;    // [32][64]

    if (tid < DA) {
        qb_s[tid] = qbuf[(size_t)b * DA + tid] + bm[tid];
        wv_s[tid] = Wv[tid];
    }
    for (int i = tid; i < 2 * (TT + KW - 1); i += 256) {
        int c = i / 158, j = i % 158;
        int t = t0 - PADW + j;
        attw_s[c * 160 + j] = (t >= 0 && t < T_) ? attw[((size_t)b * 2 + c) * T_ + t] : 0.f;
    }
    for (int i = tid; i < NF * 2 * KW; i += 256) {
        int f = i / 62, r = i % 62;
        wconv_s[f * 64 + r] = Wconv[i];
    }
    // Wloc frags -> Bbuf[1]
    for (int i = tid; i < DA * NF; i += 256) {
        int a = i >> 5, f = i & 31;
        unsigned short h, l;
        split1_trunc(Wloc[a * NF + f], h, l);
        int off = frag_off(a, f);
        Bbuf[1][off] = h;
        Bbuf[1][off + 4096] = l;
    }
    __syncthreads();

    // phase 2: conv -> Abuf[1] (XOR-swizzled fp32 layout)
    for (int i = tid; i < TT * NF; i += 256) {
        int t = i >> 5, f = i & 31;
        const float* w0 = wconv_s + f * 64;
        const float* a0 = attw_s + t;
        const float* a1 = attw_s + 160 + t;
        float s = 0.f;
#pragma unroll
        for (int k = 0; k < KW; ++k) s += w0[k] * a0[k] + w0[31 + k] * a1[k];
        int unit = t * 8 + ((f >> 2) ^ (t & 7));
        Abuf[1][unit * 4 + (f & 3)] = s;
    }
    __syncthreads();

    f32x4 acc[4][4];
#pragma unroll
    for (int mi = 0; mi < 4; ++mi)
#pragma unroll
        for (int ni = 0; ni < 4; ++ni) {
            f32x4 z = {0.f, 0.f, 0.f, 0.f};
            acc[mi][ni] = z;
        }

    // per-lane A source base: row (lane>>3), swizzled col piece (lane&7)^((lane>>3)&7)
    const size_t mem_base = ((size_t)b * T_ + t0) * DE;
    const float* a_lane = mem + mem_base + (size_t)(lane >> 3) * DE
                          + (((lane & 7) ^ ((lane >> 3) & 7)) << 2);
    const unsigned short* b_lane = Bsw + wave * 2048 + lane * 8;

    auto issue_A = [&](int c, int buf) {
#pragma unroll
        for (int it = 0; it < 4; ++it) {
            int id = wave * 4 + it;   // rows id*8 .. id*8+7
            __builtin_amdgcn_global_load_lds(
                (const __attribute__((address_space(1))) unsigned*)(a_lane + (size_t)id * 8 * DE + c * 32),
                (__attribute__((address_space(3))) unsigned*)((char*)Abuf[buf] + id * 1024), 16, 0, 0);
        }
    };
    auto issue_B = [&](int c, int buf) {
#pragma unroll
        for (int it = 0; it < 4; ++it) {
            __builtin_amdgcn_global_load_lds(
                (const __attribute__((address_space(1))) unsigned*)(b_lane + (size_t)c * 8192 + it * 512),
                (__attribute__((address_space(3))) unsigned*)((char*)Bbuf[buf] + wave * 4096 + it * 1024), 16, 0, 0);
        }
    };

    const int sw = m15 & 7;
    auto mfma_step = [&](const float* Ab, const unsigned short* Bb) {
        BF8 ah[4], al[4];
#pragma unroll
        for (int mi = 0; mi < 4; ++mi) {
            int r = (wm * 4 + mi) * 16 + m15;
            const float* p1 = Ab + ((r * 8 + ((kg << 1) ^ sw)) << 2);
            const float* p2 = Ab + ((r * 8 + (((kg << 1) | 1) ^ sw)) << 2);
            f32x4 a0 = *(const f32x4*)p1;   // k = kg*8 .. +3
            f32x4 a1 = *(const f32x4*)p2;   // k = kg*8+4 .. +7
            split2_trunc(a0.x, a0.y, ah[mi].u[0], al[mi].u[0]);
            split2_trunc(a0.z, a0.w, ah[mi].u[1], al[mi].u[1]);
            split2_trunc(a1.x, a1.y, ah[mi].u[2], al[mi].u[2]);
            split2_trunc(a1.z, a1.w, ah[mi].u[3], al[mi].u[3]);
        }
#pragma unroll
        for (int ni = 0; ni < 4; ++ni) {
            const unsigned short* q = Bb + ((wn * 4 + ni) * 64 + lane) * 8;
            bf16x8 bh = *(const bf16x8*)q;
            bf16x8 bl = *(const bf16x8*)(q + 4096);
#pragma unroll
            for (int mi = 0; mi < 4; ++mi) {
                acc[mi][ni] = __builtin_amdgcn_mfma_f32_16x16x32_bf16(ah[mi].v, bh, acc[mi][ni], 0, 0, 0);
                acc[mi][ni] = __builtin_amdgcn_mfma_f32_16x16x32_bf16(ah[mi].v, bl, acc[mi][ni], 0, 0, 0);
                acc[mi][ni] = __builtin_amdgcn_mfma_f32_16x16x32_bf16(al[mi].v, bh, acc[mi][ni], 0, 0, 0);
            }
        }
    };

    // prefetch chunk 0 while conv-chunk MFMA runs
    issue_A(0, 0);
    issue_B(0, 0);
    mfma_step(Abuf[1], Bbuf[1]);   // conv/location chunk
    __syncthreads();               // drains chunk-0 DMA

    for (int c = 0; c < 16; ++c) {
        if (c < 15) {
            issue_A(c + 1, (c + 1) & 1);
            issue_B(c + 1, (c + 1) & 1);
        }
        mfma_step(Abuf[c & 1], Bbuf[c & 1]);
        __syncthreads();           // reads done + drains c+1 DMA
    }

    // epilogue: e[t] = bv + sum_a wv[a]*tanh(acc + qb[a])
    float wvr[4], qbr[4];
#pragma unroll
    for (int ni = 0; ni < 4; ++ni) {
        int a = wn * 64 + ni * 16 + m15;
        wvr[ni] = wv_s[a];
        qbr[ni] = qb_s[a];
    }
    float bvv = bv[0];
#pragma unroll
    for (int mi = 0; mi < 4; ++mi) {
#pragma unroll
        for (int reg = 0; reg < 4; ++reg) {
            float s = 0.f;
#pragma unroll
            for (int ni = 0; ni < 4; ++ni)
                s += wvr[ni] * fast_tanh(acc[mi][ni][reg] + qbr[ni]);
            s += __shfl_xor(s, 1, 64);
            s += __shfl_xor(s, 2, 64);
            s += __shfl_xor(s, 4, 64);
            s += __shfl_xor(s, 8, 64);
            if (m15 == 0)
                e_part[wn][wm * 64 + mi * 16 + kg * 4 + reg] = s;
        }
    }
    __syncthreads();
    if (tid < TT)
        e_out[(size_t)b * T_ + t0 + tid] = e_part[0][tid] + e_part[1][tid] + bvv;
}

// ---- softmax over T per b ----
__global__ __launch_bounds__(256) void softmax_kernel(const float* __restrict__ e,
                                                      float* __restrict__ wout) {
    int b = blockIdx.x;
    int tid = threadIdx.x;
    __shared__ float red[4];
    float v[8];
    float m = -1e30f;
#pragma unroll
    for (int r = 0; r < 8; ++r) {
        v[r] = e[(size_t)b * T_ + r * 256 + tid];
        m = fmaxf(m, v[r]);
    }
#pragma unroll
    for (int off = 1; off < 64; off <<= 1) m = fmaxf(m, __shfl_xor(m, off, 64));
    if ((tid & 63) == 0) red[tid >> 6] = m;
    __syncthreads();
    m = fmaxf(fmaxf(red[0], red[1]), fmaxf(red[2], red[3]));
    __syncthreads();
    float s = 0.f;
#pragma unroll
    for (int r = 0; r < 8; ++r) {
        v[r] = expf(v[r] - m);
        s += v[r];
    }
#pragma unroll
    for (int off = 1; off < 64; off <<= 1) s += __shfl_xor(s, off, 64);
    if ((tid & 63) == 0) red[tid >> 6] = s;
    __syncthreads();
    s = red[0] + red[1] + red[2] + red[3];
    float inv = 1.0f / s;
#pragma unroll
    for (int r = 0; r < 8; ++r) wout[(size_t)b * T_ + r * 256 + tid] = v[r] * inv;
}

// ---- context partials: 32 chunks of 64 t-rows ----
__global__ __launch_bounds__(256) void ctx_partial_kernel(const float* __restrict__ mem,
                                                          const float* __restrict__ w,
                                                          float* __restrict__ partial) {
    int b = blockIdx.y, tc = blockIdx.x;
    int tid = threadIdx.x;
    __shared__ float ws_s[64];
    __shared__ float red[512];
    if (tid < 64) ws_s[tid] = w[(size_t)b * T_ + tc * 64 + tid];
    __syncthreads();
    int d = (tid & 127) * 4;
    int th = tid >> 7;
    const float* mp = mem + ((size_t)b * T_ + tc * 64 + th * 32) * DE + d;
    float a0 = 0.f, a1 = 0.f, a2 = 0.f, a3 = 0.f;
#pragma unroll 8
    for (int t = 0; t < 32; ++t) {
        float4 v = *(const float4*)(mp + (size_t)t * DE);
        float wv = ws_s[th * 32 + t];
        a0 += wv * v.x; a1 += wv * v.y; a2 += wv * v.z; a3 += wv * v.w;
    }
    if (th == 1) {
        float* r = red + (tid & 127) * 4;
        r[0] = a0; r[1] = a1; r[2] = a2; r[3] = a3;
    }
    __syncthreads();
    if (th == 0) {
        const float* r = red + tid * 4;
        float* pp = partial + ((size_t)b * 32 + tc) * DE + d;
        pp[0] = a0 + r[0]; pp[1] = a1 + r[1]; pp[2] = a2 + r[2]; pp[3] = a3 + r[3];
    }
}

// ---- reduce partials -> context ----
__global__ __launch_bounds__(512) void ctx_reduce_kernel(const float* __restrict__ partial,
                                                         float* __restrict__ ctx) {
    int b = blockIdx.x;
    int d = threadIdx.x;
    float s = 0.f;
#pragma unroll
    for (int j = 0; j < 32; ++j) s += partial[((size_t)b * 32 + j) * DE + d];
    ctx[(size_t)b * DE + d] = s;
}

extern "C" void kernel_launch(void* const* d_in, const int* in_sizes, int n_in,
                              void* d_out, int out_size, void* d_ws, size_t ws_size,
                              hipStream_t stream) {
    const float* query  = (const float*)d_in[0];
    const float* memory = (const float*)d_in[1];
    const float* attw   = (const float*)d_in[2];
    const float* Wq     = (const float*)d_in[3];
    const float* bq     = (const float*)d_in[4];
    const float* Wm     = (const float*)d_in[5];
    const float* bm     = (const float*)d_in[6];
    const float* Wconv  = (const float*)d_in[7];
    const float* Wloc   = (const float*)d_in[8];
    const float* Wv     = (const float*)d_in[9];
    const float* bv     = (const float*)d_in[10];

    float* out = (float*)d_out;
    float* ctx_out = out;          // [64,512]
    float* w_out = out + B_ * DE;  // [64,2048]

    float* ws = (float*)d_ws;
    float* qbuf = ws;                                  // 8192 f
    float* ebuf = qbuf + B_ * DA;                      // 131072 f
    float* partial = ebuf + (size_t)B_ * T_;           // 1048576 f
    unsigned short* Bsw = (unsigned short*)(partial + (size_t)B_ * 32 * DE);  // 131072 ush

    prep_kernel<<<dim3(DA * DE / 256), dim3(256), 0, stream>>>(Wm, Bsw);
    q_kernel<<<dim3(B_), dim3(128), 0, stream>>>(query, Wq, bq, qbuf);
    energy_kernel<<<dim3(T_ / TT, B_), dim3(256), 0, stream>>>(
        memory, attw, Bsw, bm, Wconv, Wloc, Wv, bv, qbuf, ebuf);
    softmax_kernel<<<dim3(B_), dim3(256), 0, stream>>>(ebuf, w_out);
    ctx_partial_kernel<<<dim3(32, B_), dim3(256), 0, stream>>>(memory, w_out, partial);
    ctx_reduce_kernel<<<dim3(B_), dim3(512), 0, stream>>>(partial, ctx_out);
}